// Round 4
// baseline (174.133 us; speedup 1.0000x reference)
//
#include <hip/hip_runtime.h>
#include <math.h>

// Problem constants (fixed by setup_inputs: B=8, H=W=64, C=256, sr=8)
static constexpr int Bb  = 8;
static constexpr int Nn  = 4096;   // H*W
static constexpr int Cc  = 256;
static constexpr int Wd  = 64;     // image H == W
static constexpr int N1c = 256;    // 16x16 after 4x down
static constexpr int N2c = 64;     // 8x8 after 8x down

typedef __attribute__((ext_vector_type(8)))  short s16x8;   // 8 bf16 (4 VGPR)
typedef __attribute__((ext_vector_type(4)))  float f32x4v;  // MFMA acc

__device__ __forceinline__ unsigned short f2bf(float f) {
  unsigned u = __float_as_uint(f);
  unsigned r = (u + 0x7fffu + ((u >> 16) & 1u)) >> 16;   // RTN-even
  return (unsigned short)r;
}
__device__ __forceinline__ float bf2f(unsigned short h) {
  return __uint_as_float(((unsigned)h) << 16);
}

// ============ prepass: split 4 [256x256] fp32 weights into bf16 hi/lo ============
__global__ __launch_bounds__(256)
void cvt4(const float* __restrict__ w0, const float* __restrict__ w1,
          const float* __restrict__ w2, const float* __restrict__ w3,
          unsigned short* __restrict__ hi, unsigned short* __restrict__ lo) {
  const int wsel = blockIdx.y;
  const float* w = wsel == 0 ? w0 : wsel == 1 ? w1 : wsel == 2 ? w2 : w3;
  const int i = (blockIdx.x * 256 + threadIdx.x) * 4;
  float4 v = *(const float4*)(w + i);
  unsigned short h0 = f2bf(v.x), h1 = f2bf(v.y), h2 = f2bf(v.z), h3 = f2bf(v.w);
  ushort4 hh = make_ushort4(h0, h1, h2, h3);
  ushort4 ll = make_ushort4(f2bf(v.x - bf2f(h0)), f2bf(v.y - bf2f(h1)),
                            f2bf(v.z - bf2f(h2)), f2bf(v.w - bf2f(h3)));
  *(ushort4*)(hi + (size_t)wsel * 65536 + i) = hh;
  *(ushort4*)(lo + (size_t)wsel * 65536 + i) = ll;
}

// ============ GEMM v2: LDS-free, direct-from-global MFMA fragments ==============
// Out[m,n] = sum_k A[m,k]*W[n,k] (+bias), 3-term split-bf16.
// Block = 4 waves = 64 rows x 256 cols; wave owns cols wid*64..+63 (4x4 16x16 tiles).
// A-frag (fp32->bf16 hi/lo in-register) and W-frags (pre-split) load straight from
// global as 16-32B/lane; W (256KB) is L2-resident, A rows L1-shared across waves.
// No LDS, no barriers -> pure VMEM/VALU/MFMA pipeline.
template<bool BIAS>
__global__ __launch_bounds__(256)
void gemm_direct(const float* __restrict__ A, const unsigned short* __restrict__ Wh,
                 const unsigned short* __restrict__ Wl, const float* __restrict__ bias,
                 float* __restrict__ Out) {
  const int tid  = threadIdx.x;
  const int lane = tid & 63, wid = tid >> 6;
  const int qi = lane & 15, g = lane >> 4;
  const int m0 = blockIdx.x * 64;

  const float*          Ab  = A  + (size_t)(m0 + qi) * 256 + g * 8;
  const unsigned short* WhB = Wh + (size_t)(wid * 64 + qi) * 256 + g * 8;
  const unsigned short* WlB = Wl + (size_t)(wid * 64 + qi) * 256 + g * 8;

  f32x4v acc[4][4] = {};   // [mt][nt]

  for (int k0 = 0; k0 < 256; k0 += 32) {
    // ---- A fragments: load fp32, split to bf16 hi/lo in-register ----
    s16x8 ah[4], al[4];
#pragma unroll
    for (int mt = 0; mt < 4; ++mt) {
      float fv[8];
      *(float4*)&fv[0] = *(const float4*)(Ab + (size_t)mt * 16 * 256 + k0);
      *(float4*)&fv[4] = *(const float4*)(Ab + (size_t)mt * 16 * 256 + k0 + 4);
#pragma unroll
      for (int j = 0; j < 8; ++j) {
        unsigned short h = f2bf(fv[j]);
        ah[mt][j] = (short)h;
        al[mt][j] = (short)f2bf(fv[j] - bf2f(h));
      }
    }
    // ---- W fragments direct from global (L2-hot), 3-term MFMA ----
#pragma unroll
    for (int nt = 0; nt < 4; ++nt) {
      s16x8 bh = *(const s16x8*)(WhB + (size_t)nt * 16 * 256 + k0);
      s16x8 bl = *(const s16x8*)(WlB + (size_t)nt * 16 * 256 + k0);
#pragma unroll
      for (int mt = 0; mt < 4; ++mt) {
        acc[mt][nt] = __builtin_amdgcn_mfma_f32_16x16x32_bf16(ah[mt], bh, acc[mt][nt], 0, 0, 0);
        acc[mt][nt] = __builtin_amdgcn_mfma_f32_16x16x32_bf16(ah[mt], bl, acc[mt][nt], 0, 0, 0);
        acc[mt][nt] = __builtin_amdgcn_mfma_f32_16x16x32_bf16(al[mt], bh, acc[mt][nt], 0, 0, 0);
      }
    }
  }
  // ---- epilogue: C col=lane&15, row=(lane>>4)*4+reg ----
#pragma unroll
  for (int nt = 0; nt < 4; ++nt) {
    const int col = wid * 64 + nt * 16 + qi;
    const float bv = BIAS ? bias[col] : 0.f;
#pragma unroll
    for (int mt = 0; mt < 4; ++mt) {
#pragma unroll
      for (int r = 0; r < 4; ++r) {
        const int row = m0 + mt * 16 + g * 4 + r;
        Out[(size_t)row * 256 + col] = acc[mt][nt][r] + bv;
      }
    }
  }
}

// =============== fused: depthwise KSxKS stride-KS conv + bias + LN + exact GELU =======
template<int KS, int HO>
__global__ __launch_bounds__(256)
void down_ln_gelu(const float* __restrict__ x, const float* __restrict__ w,
                  const float* __restrict__ cb, const float* __restrict__ g,
                  const float* __restrict__ lb, float* __restrict__ xo) {
  const int b = blockIdx.y;
  const int n1 = blockIdx.x;
  const int i = n1 / HO, j = n1 % HO;
  const int c = threadIdx.x;
  const float* wc = w + c * KS * KS;
  const float* xb = x + ((size_t)b * Nn) * Cc + c;
  float acc = cb[c];
#pragma unroll
  for (int dy = 0; dy < KS; ++dy) {
#pragma unroll
    for (int dx = 0; dx < KS; ++dx) {
      int n = (i * KS + dy) * Wd + (j * KS + dx);
      acc = fmaf(wc[dy * KS + dx], xb[(size_t)n * Cc], acc);
    }
  }
  float s = acc, s2 = acc * acc;
#pragma unroll
  for (int off = 32; off; off >>= 1) {
    s  += __shfl_down(s, off);
    s2 += __shfl_down(s2, off);
  }
  __shared__ float rs[4], rq[4];
  if ((c & 63) == 0) { rs[c >> 6] = s; rq[c >> 6] = s2; }
  __syncthreads();
  float sum = rs[0] + rs[1] + rs[2] + rs[3];
  float sq  = rq[0] + rq[1] + rq[2] + rq[3];
  float mean = sum * (1.f / Cc);
  float var  = sq * (1.f / Cc) - mean * mean;
  float xn = (acc - mean) * rsqrtf(var + 1e-5f) * g[c] + lb[c];
  float gel = 0.5f * xn * (1.f + erff(xn * 0.70710678118654752440f));
  xo[((size_t)b * (HO * HO) + n1) * Cc + c] = gel;
}

// =============== v_new = v + dwconv3x3(v) + bias  (v = channels 128.. of kv) =========
template<int HS>
__global__ __launch_bounds__(128)
void vconv(const float* __restrict__ kv, const float* __restrict__ w,
           const float* __restrict__ bias, float* __restrict__ vo) {
  constexpr int NS = HS * HS;
  const int b = blockIdx.y;
  const int n1 = blockIdx.x;
  const int i = n1 / HS, j = n1 % HS;
  const int c = threadIdx.x;
  const float* vb = kv + ((size_t)b * NS) * Cc + 128 + c;
  const float* wc = w + c * 9;
  float acc = bias[c];
#pragma unroll
  for (int dy = 0; dy < 3; ++dy) {
    int ii = i + dy - 1;
    if (ii < 0 || ii >= HS) continue;
#pragma unroll
    for (int dx = 0; dx < 3; ++dx) {
      int jj = j + dx - 1;
      if (jj < 0 || jj >= HS) continue;
      acc = fmaf(wc[dy * 3 + dx], vb[(size_t)(ii * HS + jj) * Cc], acc);
    }
  }
  vo[((size_t)b * NS + n1) * 128 + c] = acc + vb[(size_t)n1 * Cc];
}

// =============== attention v3: MFMA, swapped QK^T, exact softmax =====================
template<int NS>
__global__ __launch_bounds__(256, 2)
void attn_mfma(float* __restrict__ qo, const float* __restrict__ kv,
               const float* __restrict__ vnew, const int branch) {
  constexpr int NT = NS / 16, NC = NS / 32, PS = NS + 8;
  constexpr float KC = 0.17677669529663688f * 1.4426950408889634f; // scale*log2e
  __shared__ unsigned short Klds[NS][40];
  constexpr int VB = NS * 36 * 4, PB = 4 * 16 * PS * 2;
  constexpr int USZ = (VB > PB) ? VB : PB;
  __shared__ __align__(16) char Ubuf[USZ];
  float (*vs)[36] = (float (*)[36])Ubuf;

  const int tid = threadIdx.x, lane = tid & 63, wid = tid >> 6;
  const int g = lane >> 4, qi = lane & 15;
  const int h = blockIdx.y, b = blockIdx.z;
  const int ck = h * 32;
  const int cq = branch * 128 + h * 32;

  for (int r = tid; r < NS; r += 256) {
    const float* kp = kv   + ((size_t)(b * NS + r)) * 256 + ck;
    const float* vp = vnew + ((size_t)(b * NS + r)) * 128 + ck;
    float kf[32];
#pragma unroll
    for (int i = 0; i < 8; ++i) *(float4*)&kf[i * 4] = *(const float4*)(kp + i * 4);
    unsigned kw[16];
#pragma unroll
    for (int i = 0; i < 16; ++i)
      kw[i] = f2bf(kf[2 * i]) | ((unsigned)f2bf(kf[2 * i + 1]) << 16);
#pragma unroll
    for (int i = 0; i < 4; ++i)
      *(uint4*)&Klds[r][i * 8] = make_uint4(kw[i*4], kw[i*4+1], kw[i*4+2], kw[i*4+3]);
#pragma unroll
    for (int i = 0; i < 8; ++i) *(float4*)&vs[r][i * 4] = *(const float4*)(vp + i * 4);
  }
  __syncthreads();

  s16x8 vt[2][NC];
#pragma unroll
  for (int dt = 0; dt < 2; ++dt)
#pragma unroll
    for (int c = 0; c < NC; ++c)
#pragma unroll
      for (int j = 0; j < 8; ++j)
        vt[dt][c][j] = (short)f2bf(vs[32 * c + 8 * g + j][16 * dt + qi]);
  __syncthreads();   // V region reused as P below

  unsigned short* Pw = (unsigned short*)Ubuf + (size_t)(wid * 16 + qi) * PS;

  for (int qt = 0; qt < 4; ++qt) {
    const int qrow = blockIdx.x * 256 + wid * 64 + qt * 16 + qi;
    float* qp = qo + ((size_t)b * Nn + qrow) * 256 + cq;
    float qf0[4], qf1[4];
    *(float4*)qf0 = *(const float4*)(qp + 8 * g);
    *(float4*)qf1 = *(const float4*)(qp + 8 * g + 4);
    s16x8 qfrag;
#pragma unroll
    for (int j = 0; j < 4; ++j) qfrag[j] = (short)f2bf(qf0[j]);
#pragma unroll
    for (int j = 0; j < 4; ++j) qfrag[4 + j] = (short)f2bf(qf1[j]);
    f32x4v s[NT];
#pragma unroll
    for (int t = 0; t < NT; ++t) {
      s16x8 kf = *(const s16x8*)&Klds[16 * t + qi][8 * g];
      s[t] = __builtin_amdgcn_mfma_f32_16x16x32_bf16(kf, qfrag,
                                                     (f32x4v){0.f, 0.f, 0.f, 0.f}, 0, 0, 0);
    }
    float m = s[0][0];
#pragma unroll
    for (int t = 0; t < NT; ++t)
      m = fmaxf(m, fmaxf(fmaxf(s[t][0], s[t][1]), fmaxf(s[t][2], s[t][3])));
    m = fmaxf(m, __shfl_xor(m, 16));
    m = fmaxf(m, __shfl_xor(m, 32));
    float l = 0.f;
#pragma unroll
    for (int t = 0; t < NT; ++t)
#pragma unroll
      for (int r = 0; r < 4; ++r) {
        float p = exp2f((s[t][r] - m) * KC);
        s[t][r] = p; l += p;
      }
    l += __shfl_xor(l, 16);
    l += __shfl_xor(l, 32);
#pragma unroll
    for (int t = 0; t < NT; ++t) {
      unsigned w0 = f2bf(s[t][0]) | ((unsigned)f2bf(s[t][1]) << 16);
      unsigned w1 = f2bf(s[t][2]) | ((unsigned)f2bf(s[t][3]) << 16);
      *(uint2*)&Pw[16 * t + 4 * g] = make_uint2(w0, w1);
    }
    f32x4v o0 = {0.f, 0.f, 0.f, 0.f}, o1 = {0.f, 0.f, 0.f, 0.f};
#pragma unroll
    for (int c = 0; c < NC; ++c) {
      s16x8 pf = *(const s16x8*)&Pw[32 * c + 8 * g];
      o0 = __builtin_amdgcn_mfma_f32_16x16x32_bf16(vt[0][c], pf, o0, 0, 0, 0);
      o1 = __builtin_amdgcn_mfma_f32_16x16x32_bf16(vt[1][c], pf, o1, 0, 0, 0);
    }
    const float inv = 1.f / l;
    float4 O0 = make_float4(o0[0] * inv, o0[1] * inv, o0[2] * inv, o0[3] * inv);
    float4 O1 = make_float4(o1[0] * inv, o1[1] * inv, o1[2] * inv, o1[3] * inv);
    *(float4*)(qp + 4 * g)      = O0;
    *(float4*)(qp + 16 + 4 * g) = O1;
  }
}

extern "C" void kernel_launch(void* const* d_in, const int* in_sizes, int n_in,
                              void* d_out, int out_size, void* d_ws, size_t ws_size,
                              hipStream_t stream) {
  const float* x      = (const float*)d_in[0];
  const float* q_w    = (const float*)d_in[1];
  const float* kv1_w  = (const float*)d_in[2];
  const float* kv2_w  = (const float*)d_in[3];
  const float* proj_w = (const float*)d_in[4];
  const float* proj_b = (const float*)d_in[5];
  const float* sr1_w  = (const float*)d_in[6];
  const float* sr1_b  = (const float*)d_in[7];
  const float* sr2_w  = (const float*)d_in[8];
  const float* sr2_b  = (const float*)d_in[9];
  const float* ln1_g  = (const float*)d_in[10];
  const float* ln1_b  = (const float*)d_in[11];
  const float* ln2_g  = (const float*)d_in[12];
  const float* ln2_b  = (const float*)d_in[13];
  const float* lc1_w  = (const float*)d_in[14];
  const float* lc1_b  = (const float*)d_in[15];
  const float* lc2_w  = (const float*)d_in[16];
  const float* lc2_b  = (const float*)d_in[17];
  float* out = (float*)d_out;
  float* ws  = (float*)d_ws;

  float* q   = ws;                                   // [B,N,C] (becomes o in-place)
  float* x1  = q   + (size_t)Bb * Nn  * Cc;
  float* kv1 = x1  + (size_t)Bb * N1c * Cc;
  float* vn1 = kv1 + (size_t)Bb * N1c * Cc;
  float* x2  = vn1 + (size_t)Bb * N1c * (Cc / 2);
  float* kv2 = x2  + (size_t)Bb * N2c * Cc;
  float* vn2 = kv2 + (size_t)Bb * N2c * Cc;
  float* fend = vn2 + (size_t)Bb * N2c * (Cc / 2);
  unsigned short* wh = (unsigned short*)fend;        // [4][65536] hi
  unsigned short* wl = wh + (size_t)4 * 65536;       // [4][65536] lo

  cvt4<<<dim3(64, 4), 256, 0, stream>>>(q_w, kv1_w, kv2_w, proj_w, wh, wl);
  gemm_direct<false><<<512, 256, 0, stream>>>(x, wh, wl, nullptr, q);
  down_ln_gelu<4, 16><<<dim3(N1c, Bb), 256, 0, stream>>>(x, sr1_w, sr1_b, ln1_g, ln1_b, x1);
  down_ln_gelu<8, 8><<<dim3(N2c, Bb), 256, 0, stream>>>(x, sr2_w, sr2_b, ln2_g, ln2_b, x2);
  gemm_direct<false><<<32, 256, 0, stream>>>(x1, wh + 65536,     wl + 65536,     nullptr, kv1);
  gemm_direct<false><<<8,  256, 0, stream>>>(x2, wh + 2 * 65536, wl + 2 * 65536, nullptr, kv2);
  vconv<16><<<dim3(N1c, Bb), 128, 0, stream>>>(kv1, lc1_w, lc1_b, vn1);
  vconv<8> <<<dim3(N2c, Bb), 128, 0, stream>>>(kv2, lc2_w, lc2_b, vn2);
  attn_mfma<256><<<dim3(16, 4, Bb), 256, 0, stream>>>(q, kv1, vn1, 0);
  attn_mfma<64> <<<dim3(16, 4, Bb), 256, 0, stream>>>(q, kv2, vn2, 1);
  gemm_direct<true><<<512, 256, 0, stream>>>(q, wh + 3 * 65536, wl + 3 * 65536, proj_b, out);
}